// Round 13
// baseline (634.961 us; speedup 1.0000x reference)
//
#include <hip/hip_runtime.h>
#include <hip/hip_bf16.h>
#include <math.h>
#include <stdint.h>

#define DDIM 512
#define QN   256
#define QH   128            // queries per half (per block)
#define CROWS 256           // rows per chunk = 8 waves x 32
#define WAVES 8
#define NT   512
#define KNN  5
#define BIGF 3.0e38f

typedef __attribute__((ext_vector_type(8))) short bf16x8;
typedef __attribute__((ext_vector_type(4))) float f32x4;

#define SB0() __builtin_amdgcn_sched_barrier(0)

__device__ __forceinline__ void gload16(const void* g, void* l) {
    __builtin_amdgcn_global_load_lds(
        (const __attribute__((address_space(1))) void*)g,
        (__attribute__((address_space(3))) void*)l, 16, 0, 0);
}

__device__ __forceinline__ bf16x8 pack8(float4 a, float4 b) {
    union { bf16x8 v; __hip_bfloat162 h[4]; } u;
    u.h[0] = __float22bfloat162_rn(make_float2(a.x, a.y));
    u.h[1] = __float22bfloat162_rn(make_float2(a.z, a.w));
    u.h[2] = __float22bfloat162_rn(make_float2(b.x, b.y));
    u.h[3] = __float22bfloat162_rn(make_float2(b.z, b.w));
    return u.v;
}
__device__ __forceinline__ float sq8(float4 a, float4 b, float s) {
    s = fmaf(a.x,a.x,s); s = fmaf(a.y,a.y,s); s = fmaf(a.z,a.z,s); s = fmaf(a.w,a.w,s);
    s = fmaf(b.x,b.x,s); s = fmaf(b.y,b.y,s); s = fmaf(b.z,b.z,s); s = fmaf(b.w,b.w,s);
    return s;
}

// Packed top-5 insert (idx in low 8 mantissa bits). Static indices only.
__device__ __forceinline__ void t5p_insert(float (&s)[KNN], float v) {
    if (v < s[4]) {
        s[4] = v;
        if (s[4] < s[3]) { float t = s[3]; s[3] = s[4]; s[4] = t; }
        if (s[3] < s[2]) { float t = s[2]; s[2] = s[3]; s[3] = t; }
        if (s[2] < s[1]) { float t = s[1]; s[1] = s[2]; s[2] = t; }
        if (s[1] < s[0]) { float t = s[0]; s[0] = s[1]; s[1] = t; }
    }
}
__device__ __forceinline__ void t5_insert(float (&s)[KNN], int (&ix)[KNN], float v, int vi) {
    if (v < s[4]) {
        s[4] = v; ix[4] = vi;
        if (s[4] < s[3]) { float t = s[3]; s[3] = s[4]; s[4] = t; int u = ix[3]; ix[3] = ix[4]; ix[4] = u; }
        if (s[3] < s[2]) { float t = s[2]; s[2] = s[3]; s[3] = t; int u = ix[2]; ix[2] = ix[3]; ix[3] = u; }
        if (s[2] < s[1]) { float t = s[1]; s[1] = s[2]; s[2] = t; int u = ix[1]; ix[1] = ix[2]; ix[2] = u; }
        if (s[1] < s[0]) { float t = s[0]; s[0] = s[1]; s[1] = t; int u = ix[0]; ix[0] = ix[1]; ix[1] = u; }
    }
}

// Phase 0: queries f32 -> bf16 in LANE-ORDER fragment layout:
// qfrag[qb][ks][lane]*16B, lane = lq*16 + l15  <->  (q = qb*16+l15, k = ks*32+lq*8)
__global__ void conv_q(const float* __restrict__ emb, unsigned short* __restrict__ qfrag) {
    int t = blockIdx.x * 256 + threadIdx.x;     // 16384 threads: [qb][ks][lane]
    int l   = t & 63;
    int ks  = (t >> 6) & 15;
    int qb  = t >> 10;
    int q   = qb * 16 + (l & 15);
    int k   = ks * 32 + (l >> 4) * 8;
    const float* p = emb + (size_t)q * DDIM + k;
    float4 f0 = *(const float4*)(p);
    float4 f1 = *(const float4*)(p + 4);
    *(bf16x8*)(qfrag + (size_t)t * 8) = pack8(f0, f1);
}

// One half-K-step (K=32): pack current slab, pinned refill at distance 2,
// setprio'd 16-MFMA cluster against LDS B-frags.
#define HALF_STEP(S00,S01,S10,S11, JJ, REFILL_OFF, DO_REFILL) \
    { bf16x8 a0 = pack8(S00, S01); bf16x8 a1 = pack8(S10, S11); \
      sq0 = sq8(S00, S01, sq0); sq1 = sq8(S10, S11, sq1); \
      SB0(); \
      if (DO_REFILL) { \
          S00 = *(const float4*)(pA0 + (REFILL_OFF)); \
          S01 = *(const float4*)(pA0 + (REFILL_OFF) + 4); \
          S10 = *(const float4*)(pA1 + (REFILL_OFF)); \
          S11 = *(const float4*)(pA1 + (REFILL_OFF) + 4); \
      } \
      SB0(); \
      __builtin_amdgcn_s_setprio(1); \
      _Pragma("unroll") \
      for (int g = 0; g < 8; ++g) { \
          bf16x8 br = *(const bf16x8*)(sm.b + (g * 8 + (JJ)) * 1024 + lane * 16); \
          acc[0][g] = __builtin_amdgcn_mfma_f32_16x16x32_bf16(a0, br, acc[0][g], 0, 0, 0); \
          acc[1][g] = __builtin_amdgcn_mfma_f32_16x16x32_bf16(a1, br, acc[1][g], 0, 0, 0); \
      } \
      __builtin_amdgcn_s_setprio(0); \
    }

// Phase A: block = (chunk of 256 rows, q-half of 128). B-half staged as TWO
// 64-KB K-chunks (LDS 65.5 KB -> 2 blocks/CU); inner loops barrier-free;
// A streams HBM->reg with PINNED distance-2 E/O prefetch (refills cross the
// chunk boundary); each mem byte read once per half.
__global__ __launch_bounds__(NT, 4) void knn_partial(
        const float* __restrict__ mem, const unsigned short* __restrict__ qfrag,
        float* __restrict__ cand, int N, int NCH) {
    __shared__ union {
        char  b[QH * 256 * 2];          // 64 KB: frag (qb_local*8 + ks_local)*1024
        float mbuf[WAVES][QH][KNN];     // 20 KB (epilogue)
    } sm;
    __shared__ float smsq[CROWS];

    const int tid  = threadIdx.x;
    const int lane = tid & 63;
    const int w    = tid >> 6;          // 0..7
    const int l15  = lane & 15;
    const int lq   = lane >> 4;         // k-slice 0..3
    const int chunk = blockIdx.x >> 1;
    const int h     = blockIdx.x & 1;   // q-half
    const int rbase = chunk * CROWS;

    // A rows: wave w owns rows rbase+w*32 .. +31 (read once per half)
    int r0 = rbase + w * 32 + l15;      if (r0 >= N) r0 = N - 1;
    int r1 = rbase + w * 32 + 16 + l15; if (r1 >= N) r1 = N - 1;
    const float* pA0 = mem + (size_t)r0 * DDIM + lq * 8;
    const float* pA1 = mem + (size_t)r1 * DDIM + lq * 8;

    f32x4 acc[2][8];
    const f32x4 z4 = {0.f, 0.f, 0.f, 0.f};
#pragma unroll
    for (int rf = 0; rf < 2; ++rf)
#pragma unroll
        for (int g = 0; g < 8; ++g) acc[rf][g] = z4;
    float sq0 = 0.f, sq1 = 0.f;

    // E/O A-slabs (distance-2 pipeline)
    float4 e00, e01, e10, e11, o00, o01, o10, o11;

#pragma unroll
    for (int c = 0; c < 2; ++c) {
        if (c == 1) __builtin_amdgcn_s_barrier();   // chunk-0 LDS reads done
        // stage B K-chunk c: wave w stages qb_local=w, ks_local 0..7
        {
            const char* src = (const char*)qfrag
                + ((size_t)(h * 8 + w) * 16 + c * 8) * 1024 + lane * 16;
            char* dst = sm.b + (w * 8) * 1024;
#pragma unroll
            for (int i = 0; i < 8; ++i)
                gload16(src + i * 1024, dst + i * 1024);
        }
        if (c == 0) {                   // A prologue: slabs for kk=0 (E), kk=1 (O)
            e00 = *(const float4*)(pA0);      e01 = *(const float4*)(pA0 + 4);
            e10 = *(const float4*)(pA1);      e11 = *(const float4*)(pA1 + 4);
            o00 = *(const float4*)(pA0 + 32); o01 = *(const float4*)(pA0 + 36);
            o10 = *(const float4*)(pA1 + 32); o11 = *(const float4*)(pA1 + 36);
            SB0();
            asm volatile("s_waitcnt vmcnt(8)" ::: "memory");  // B landed; A flying
        } else {
            SB0();
            asm volatile("s_waitcnt vmcnt(0)" ::: "memory");  // B landed (newest)
        }
        __builtin_amdgcn_s_barrier();

#pragma unroll
        for (int j = 0; j < 8; j += 2) {
            const int kk = c * 8 + j;   // global K-step (compile-time)
            HALF_STEP(e00, e01, e10, e11, j,     (kk + 2) * 32, (kk + 2) < 16)
            HALF_STEP(o00, o01, o10, o11, j + 1, (kk + 3) * 32, (kk + 3) < 16)
        }
    }

    // ||m||^2 per row (reduce k-slices across lq)
    sq0 += __shfl_xor(sq0, 16); sq0 += __shfl_xor(sq0, 32);
    sq1 += __shfl_xor(sq1, 16); sq1 += __shfl_xor(sq1, 32);
    if (lane < 16) {
        smsq[w * 32 + lane]      = sq0;
        smsq[w * 32 + 16 + lane] = sq1;
    }
    __syncthreads();                    // all B reads done; mbuf may alias B
    float rsq0[4], rsq1[4];
    *(float4*)rsq0 = *(const float4*)&smsq[w * 32 + lq * 4];
    *(float4*)rsq1 = *(const float4*)&smsq[w * 32 + 16 + lq * 4];

    // epilogue: per q-frag g (8 per wave): packed scores over this wave's 32
    // rows -> lane top5 -> shfl merge -> mbuf[w]
#pragma unroll
    for (int g = 0; g < 8; ++g) {
        float ts[KNN] = {BIGF, BIGF, BIGF, BIGF, BIGF};
#pragma unroll
        for (int e = 0; e < 4; ++e) {
            int rl0 = w * 32 + lq * 4 + e;          // chunk-local row (frag 0)
            if (rbase + rl0 < N) {
                float sc = fmaf(-2.f, acc[0][g][e], rsq0[e]);
                t5p_insert(ts, __int_as_float((__float_as_int(sc) & ~255) | rl0));
            }
            int rl1 = rl0 + 16;                     // frag 1
            if (rbase + rl1 < N) {
                float sc = fmaf(-2.f, acc[1][g][e], rsq1[e]);
                t5p_insert(ts, __int_as_float((__float_as_int(sc) & ~255) | rl1));
            }
        }
#pragma unroll
        for (int x = 16; x <= 32; x <<= 1) {
            float os[KNN];
#pragma unroll
            for (int cc = 0; cc < KNN; ++cc) os[cc] = __shfl_xor(ts[cc], x);
#pragma unroll
            for (int cc = 0; cc < KNN; ++cc) t5p_insert(ts, os[cc]);
        }
        if (lane < 16) {
#pragma unroll
            for (int cc = 0; cc < KNN; ++cc) sm.mbuf[w][g * 16 + lane][cc] = ts[cc];
        }
    }
    __syncthreads();
    if (tid < QH) {      // q-local tid: merge 8 waves; cand[q][chunk][5]
        float fsv[KNN] = {BIGF, BIGF, BIGF, BIGF, BIGF};
#pragma unroll
        for (int ww = 0; ww < WAVES; ++ww)
#pragma unroll
            for (int cc = 0; cc < KNN; ++cc)
                t5p_insert(fsv, sm.mbuf[ww][tid][cc]);
        float* dst = cand + ((size_t)(h * QH + tid) * NCH + chunk) * KNN;
#pragma unroll
        for (int cc = 0; cc < KNN; ++cc) dst[cc] = fsv[cc];
    }
}

// Phase B: one wave per query: global top-5 over NCH*5 packed candidates,
// gather rows, exact f32 distances (immune to bf16/packing jitter), sum.
__global__ void knn_merge_exact(const float* __restrict__ emb, const float* __restrict__ mem,
                                const float* __restrict__ cand, float* __restrict__ qsum,
                                int Q, int NCH) {
    const int q = blockIdx.x;
    const int lane = threadIdx.x;  // 64
    float fs[KNN] = {BIGF, BIGF, BIGF, BIGF, BIGF};
    int   fi[KNN] = {0, 0, 0, 0, 0};
    const float* qc = cand + (size_t)q * NCH * KNN;
    for (int c = lane; c < NCH; c += 64) {
        const float* p = qc + (size_t)c * KNN;
#pragma unroll
        for (int k = 0; k < KNN; ++k) {
            float pk = p[k];
            int idx = c * CROWS + (__float_as_int(pk) & 255);
            t5_insert(fs, fi, pk, idx);
        }
    }
    __shared__ float2 ls[64][KNN];
    __shared__ int sel[KNN];
#pragma unroll
    for (int k = 0; k < KNN; ++k) ls[lane][k] = make_float2(fs[k], __int_as_float(fi[k]));
    __syncthreads();
    if (lane == 0) {
        float gs[KNN] = {BIGF, BIGF, BIGF, BIGF, BIGF};
        int   gi[KNN] = {0, 0, 0, 0, 0};
        for (int l = 0; l < 64; ++l)
#pragma unroll
            for (int k = 0; k < KNN; ++k)
                t5_insert(gs, gi, ls[l][k].x, __float_as_int(ls[l][k].y));
#pragma unroll
        for (int k = 0; k < KNN; ++k) sel[k] = gi[k];
    }
    __syncthreads();
    const float4* qp = (const float4*)(emb + (size_t)q * DDIM);
    float4 q0 = qp[lane * 2], q1 = qp[lane * 2 + 1];
    float ssum = 0.f;
    for (int k = 0; k < KNN; ++k) {
        const float4* mp = (const float4*)(mem + (size_t)sel[k] * DDIM);
        float4 m0 = mp[lane * 2], m1 = mp[lane * 2 + 1];
        float d0 = m0.x - q0.x, d1 = m0.y - q0.y, d2 = m0.z - q0.z, d3 = m0.w - q0.w;
        float d4 = m1.x - q1.x, d5 = m1.y - q1.y, d6 = m1.z - q1.z, d7 = m1.w - q1.w;
        float t = d0*d0 + d1*d1 + d2*d2 + d3*d3 + d4*d4 + d5*d5 + d6*d6 + d7*d7;
#pragma unroll
        for (int off = 32; off > 0; off >>= 1) t += __shfl_down(t, off);
        if (lane == 0) ssum += sqrtf(t);
    }
    if (lane == 0) qsum[q] = ssum;
}

__global__ void knn_reduce(const float* __restrict__ qsum, float* __restrict__ out, int Q) {
    const int lane = threadIdx.x;
    float v = 0.f;
    for (int i = lane; i < Q; i += 64) v += qsum[i];
#pragma unroll
    for (int off = 32; off > 0; off >>= 1) v += __shfl_down(v, off);
    if (lane == 0) out[0] = v / (float)(Q * KNN);
}

extern "C" void kernel_launch(void* const* d_in, const int* in_sizes, int n_in,
                              void* d_out, int out_size, void* d_ws, size_t ws_size,
                              hipStream_t stream) {
    (void)n_in; (void)out_size; (void)ws_size;
    const float* emb = (const float*)d_in[0];
    const float* mem = (const float*)d_in[1];
    const int Q   = in_sizes[0] / DDIM;       // 256
    const int N   = in_sizes[1] / DDIM;       // 200000
    const int NCH = (N + CROWS - 1) / CROWS;  // 782

    float*          cand  = (float*)d_ws;                                        // Q*NCH*5*4B ~ 4 MB
    float*          qsum  = (float*)((char*)d_ws + (size_t)Q * NCH * KNN * 4);   // 1 KB
    unsigned short* qfrag = (unsigned short*)((char*)d_ws + (size_t)Q * NCH * KNN * 4 + 1024);

    conv_q<<<64, 256, 0, stream>>>(emb, qfrag);
    knn_partial<<<NCH * 2, NT, 0, stream>>>(mem, qfrag, cand, N, NCH);
    knn_merge_exact<<<Q, 64, 0, stream>>>(emb, mem, cand, qsum, Q, NCH);
    knn_reduce<<<1, 64, 0, stream>>>(qsum, (float*)d_out, Q);
}

// Round 14
// 237.139 us; speedup vs baseline: 2.6776x; 2.6776x over previous
//
#include <hip/hip_runtime.h>
#include <hip/hip_bf16.h>
#include <math.h>
#include <stdint.h>

#define DDIM 512
#define QH   128            // queries per half (per block)
#define CROWS 128           // rows per chunk = 4 waves x 32
#define NT   256
#define KNN  5
#define NKS  16             // K steps of 32
#define BIGF 3.0e38f

typedef __attribute__((ext_vector_type(8))) short bf16x8;
typedef __attribute__((ext_vector_type(4))) float f32x4;

__device__ __forceinline__ bf16x8 pack8(float4 a, float4 b) {
    union { bf16x8 v; __hip_bfloat162 h[4]; } u;
    u.h[0] = __float22bfloat162_rn(make_float2(a.x, a.y));
    u.h[1] = __float22bfloat162_rn(make_float2(a.z, a.w));
    u.h[2] = __float22bfloat162_rn(make_float2(b.x, b.y));
    u.h[3] = __float22bfloat162_rn(make_float2(b.z, b.w));
    return u.v;
}
__device__ __forceinline__ float sq8(float4 a, float4 b, float s) {
    s = fmaf(a.x,a.x,s); s = fmaf(a.y,a.y,s); s = fmaf(a.z,a.z,s); s = fmaf(a.w,a.w,s);
    s = fmaf(b.x,b.x,s); s = fmaf(b.y,b.y,s); s = fmaf(b.z,b.z,s); s = fmaf(b.w,b.w,s);
    return s;
}

// Packed top-5 insert (idx in low 7 mantissa bits). Static indices only.
__device__ __forceinline__ void t5p_insert(float (&s)[KNN], float v) {
    if (v < s[4]) {
        s[4] = v;
        if (s[4] < s[3]) { float t = s[3]; s[3] = s[4]; s[4] = t; }
        if (s[3] < s[2]) { float t = s[2]; s[2] = s[3]; s[3] = t; }
        if (s[2] < s[1]) { float t = s[1]; s[1] = s[2]; s[2] = t; }
        if (s[1] < s[0]) { float t = s[0]; s[0] = s[1]; s[1] = t; }
    }
}
__device__ __forceinline__ void t5_insert(float (&s)[KNN], int (&ix)[KNN], float v, int vi) {
    if (v < s[4]) {
        s[4] = v; ix[4] = vi;
        if (s[4] < s[3]) { float t = s[3]; s[3] = s[4]; s[4] = t; int u = ix[3]; ix[3] = ix[4]; ix[4] = u; }
        if (s[3] < s[2]) { float t = s[2]; s[2] = s[3]; s[3] = t; int u = ix[2]; ix[2] = ix[3]; ix[3] = u; }
        if (s[2] < s[1]) { float t = s[1]; s[1] = s[2]; s[2] = t; int u = ix[1]; ix[1] = ix[2]; ix[2] = u; }
        if (s[1] < s[0]) { float t = s[0]; s[0] = s[1]; s[1] = t; int u = ix[0]; ix[0] = ix[1]; ix[1] = u; }
    }
}

// Phase 0: queries f32 -> bf16, LANE-ORDER frag layout [ks][qb][lane]:
// byte (ks*16 + qb)*1024 + lane*16  <->  (q = qb*16 + (lane&15), k = ks*32 + (lane>>4)*8)
__global__ void conv_q(const float* __restrict__ emb, unsigned short* __restrict__ qfrag) {
    int t  = blockIdx.x * 256 + threadIdx.x;    // 16384 threads
    int l  = t & 63;
    int qb = (t >> 6) & 15;
    int ks = t >> 10;
    int q  = qb * 16 + (l & 15);
    int k  = ks * 32 + (l >> 4) * 8;
    const float* p = emb + (size_t)q * DDIM + k;
    float4 f0 = *(const float4*)(p);
    float4 f1 = *(const float4*)(p + 4);
    *(bf16x8*)(qfrag + (size_t)t * 8) = pack8(f0, f1);
}

// Phase A ("no-LDS dataflow"): block = (chunk of 128 rows, q-half of 128).
// Wave = 32 rows x 128 q (acc 2x8 f32x4). B-frags load L2->reg directly from
// the 256 KB L2-resident qfrag (no LDS, no barriers, nothing to stage); A
// streams HBM->reg (read once per half; L3 absorbs the pair re-read). Latency
// hidden by 12 waves/CU.
__global__ __launch_bounds__(NT, 3) void knn_partial(
        const float* __restrict__ mem, const unsigned short* __restrict__ qfrag,
        float* __restrict__ cand, int N, int NCH) {
    __shared__ float mbuf[4][QH][KNN];   // 10 KB
    __shared__ float smsq[CROWS];

    const int tid  = threadIdx.x;
    const int lane = tid & 63;
    const int w    = tid >> 6;          // 0..3
    const int l15  = lane & 15;
    const int lq   = lane >> 4;         // k-slice 0..3
    const int chunk = blockIdx.x >> 1;
    const int h     = blockIdx.x & 1;   // q-half
    const int rbase = chunk * CROWS;

    // A rows: wave w owns rows rbase + w*32 .. +31
    int r0 = rbase + w * 32 + l15;      if (r0 >= N) r0 = N - 1;
    int r1 = rbase + w * 32 + 16 + l15; if (r1 >= N) r1 = N - 1;
    const float* pA0 = mem + (size_t)r0 * DDIM + lq * 8;
    const float* pA1 = mem + (size_t)r1 * DDIM + lq * 8;

    // B base: frag (ks*16 + h*8 + g), per-lane 16 B
    const char* bq = (const char*)qfrag + h * 8192 + lane * 16;

    f32x4 acc[2][8];
    const f32x4 z4 = {0.f, 0.f, 0.f, 0.f};
#pragma unroll
    for (int rf = 0; rf < 2; ++rf)
#pragma unroll
        for (int g = 0; g < 8; ++g) acc[rf][g] = z4;
    float sq0 = 0.f, sq1 = 0.f;

    // prologue: A slab for ks=0
    float4 a00 = *(const float4*)(pA0), a01 = *(const float4*)(pA0 + 4);
    float4 a10 = *(const float4*)(pA1), a11 = *(const float4*)(pA1 + 4);

#pragma unroll 2
    for (int ks = 0; ks < NKS; ++ks) {
        // B frags for this step: 8 x dwordx4 from L2 (issued first, longest dep)
        const char* bp = bq + (size_t)ks * 16384;
        bf16x8 b0 = *(const bf16x8*)(bp);
        bf16x8 b1 = *(const bf16x8*)(bp + 1024);
        bf16x8 b2 = *(const bf16x8*)(bp + 2048);
        bf16x8 b3 = *(const bf16x8*)(bp + 3072);
        bf16x8 b4 = *(const bf16x8*)(bp + 4096);
        bf16x8 b5 = *(const bf16x8*)(bp + 5120);
        bf16x8 b6 = *(const bf16x8*)(bp + 6144);
        bf16x8 b7 = *(const bf16x8*)(bp + 7168);
        // A prefetch for ks+1 (HBM; lands while MFMAs run)
        float4 n00, n01, n10, n11;
        if (ks + 1 < NKS) {
            n00 = *(const float4*)(pA0 + (ks + 1) * 32);
            n01 = *(const float4*)(pA0 + (ks + 1) * 32 + 4);
            n10 = *(const float4*)(pA1 + (ks + 1) * 32);
            n11 = *(const float4*)(pA1 + (ks + 1) * 32 + 4);
        }
        // pack current A + ||m||^2
        bf16x8 A0 = pack8(a00, a01);
        bf16x8 A1 = pack8(a10, a11);
        sq0 = sq8(a00, a01, sq0);
        sq1 = sq8(a10, a11, sq1);
        __builtin_amdgcn_s_setprio(1);
        acc[0][0] = __builtin_amdgcn_mfma_f32_16x16x32_bf16(A0, b0, acc[0][0], 0, 0, 0);
        acc[1][0] = __builtin_amdgcn_mfma_f32_16x16x32_bf16(A1, b0, acc[1][0], 0, 0, 0);
        acc[0][1] = __builtin_amdgcn_mfma_f32_16x16x32_bf16(A0, b1, acc[0][1], 0, 0, 0);
        acc[1][1] = __builtin_amdgcn_mfma_f32_16x16x32_bf16(A1, b1, acc[1][1], 0, 0, 0);
        acc[0][2] = __builtin_amdgcn_mfma_f32_16x16x32_bf16(A0, b2, acc[0][2], 0, 0, 0);
        acc[1][2] = __builtin_amdgcn_mfma_f32_16x16x32_bf16(A1, b2, acc[1][2], 0, 0, 0);
        acc[0][3] = __builtin_amdgcn_mfma_f32_16x16x32_bf16(A0, b3, acc[0][3], 0, 0, 0);
        acc[1][3] = __builtin_amdgcn_mfma_f32_16x16x32_bf16(A1, b3, acc[1][3], 0, 0, 0);
        acc[0][4] = __builtin_amdgcn_mfma_f32_16x16x32_bf16(A0, b4, acc[0][4], 0, 0, 0);
        acc[1][4] = __builtin_amdgcn_mfma_f32_16x16x32_bf16(A1, b4, acc[1][4], 0, 0, 0);
        acc[0][5] = __builtin_amdgcn_mfma_f32_16x16x32_bf16(A0, b5, acc[0][5], 0, 0, 0);
        acc[1][5] = __builtin_amdgcn_mfma_f32_16x16x32_bf16(A1, b5, acc[1][5], 0, 0, 0);
        acc[0][6] = __builtin_amdgcn_mfma_f32_16x16x32_bf16(A0, b6, acc[0][6], 0, 0, 0);
        acc[1][6] = __builtin_amdgcn_mfma_f32_16x16x32_bf16(A1, b6, acc[1][6], 0, 0, 0);
        acc[0][7] = __builtin_amdgcn_mfma_f32_16x16x32_bf16(A0, b7, acc[0][7], 0, 0, 0);
        acc[1][7] = __builtin_amdgcn_mfma_f32_16x16x32_bf16(A1, b7, acc[1][7], 0, 0, 0);
        __builtin_amdgcn_s_setprio(0);
        if (ks + 1 < NKS) { a00 = n00; a01 = n01; a10 = n10; a11 = n11; }
    }

    // ||m||^2 per row (reduce k-slices across lq)
    sq0 += __shfl_xor(sq0, 16); sq0 += __shfl_xor(sq0, 32);
    sq1 += __shfl_xor(sq1, 16); sq1 += __shfl_xor(sq1, 32);
    if (lane < 16) {
        smsq[w * 32 + lane]      = sq0;
        smsq[w * 32 + 16 + lane] = sq1;
    }
    __syncthreads();
    float rsq0[4], rsq1[4];
    *(float4*)rsq0 = *(const float4*)&smsq[w * 32 + lq * 4];
    *(float4*)rsq1 = *(const float4*)&smsq[w * 32 + 16 + lq * 4];

    // epilogue: per q-frag g: packed scores over this wave's 32 rows ->
    // lane top5 -> shfl merge -> mbuf[w]
#pragma unroll
    for (int g = 0; g < 8; ++g) {
        float ts[KNN] = {BIGF, BIGF, BIGF, BIGF, BIGF};
#pragma unroll
        for (int e = 0; e < 4; ++e) {
            int rl0 = w * 32 + lq * 4 + e;          // chunk-local row 0..127
            if (rbase + rl0 < N) {
                float sc = fmaf(-2.f, acc[0][g][e], rsq0[e]);
                t5p_insert(ts, __int_as_float((__float_as_int(sc) & ~127) | rl0));
            }
            int rl1 = rl0 + 16;
            if (rbase + rl1 < N) {
                float sc = fmaf(-2.f, acc[1][g][e], rsq1[e]);
                t5p_insert(ts, __int_as_float((__float_as_int(sc) & ~127) | rl1));
            }
        }
#pragma unroll
        for (int x = 16; x <= 32; x <<= 1) {
            float os[KNN];
#pragma unroll
            for (int c = 0; c < KNN; ++c) os[c] = __shfl_xor(ts[c], x);
#pragma unroll
            for (int c = 0; c < KNN; ++c) t5p_insert(ts, os[c]);
        }
        if (lane < 16) {
#pragma unroll
            for (int c = 0; c < KNN; ++c) mbuf[w][g * 16 + lane][c] = ts[c];
        }
    }
    __syncthreads();
    if (tid < QH) {      // q-local tid: merge 4 waves; cand[q][chunk][5]
        float fsv[KNN] = {BIGF, BIGF, BIGF, BIGF, BIGF};
#pragma unroll
        for (int ww = 0; ww < 4; ++ww)
#pragma unroll
            for (int c = 0; c < KNN; ++c)
                t5p_insert(fsv, mbuf[ww][tid][c]);
        float* dst = cand + ((size_t)(h * QH + tid) * NCH + chunk) * KNN;
#pragma unroll
        for (int c = 0; c < KNN; ++c) dst[c] = fsv[c];
    }
}

// Phase B: one wave per query: global top-5 over NCH*5 packed candidates,
// gather rows, exact f32 distances (immune to bf16/packing jitter), sum.
__global__ void knn_merge_exact(const float* __restrict__ emb, const float* __restrict__ mem,
                                const float* __restrict__ cand, float* __restrict__ qsum,
                                int Q, int NCH) {
    const int q = blockIdx.x;
    const int lane = threadIdx.x;  // 64
    float fs[KNN] = {BIGF, BIGF, BIGF, BIGF, BIGF};
    int   fi[KNN] = {0, 0, 0, 0, 0};
    const float* qc = cand + (size_t)q * NCH * KNN;
    for (int c = lane; c < NCH; c += 64) {
        const float* p = qc + (size_t)c * KNN;
#pragma unroll
        for (int k = 0; k < KNN; ++k) {
            float pk = p[k];
            int idx = c * CROWS + (__float_as_int(pk) & 127);
            t5_insert(fs, fi, pk, idx);
        }
    }
    __shared__ float2 ls[64][KNN];
    __shared__ int sel[KNN];
#pragma unroll
    for (int k = 0; k < KNN; ++k) ls[lane][k] = make_float2(fs[k], __int_as_float(fi[k]));
    __syncthreads();
    if (lane == 0) {
        float gs[KNN] = {BIGF, BIGF, BIGF, BIGF, BIGF};
        int   gi[KNN] = {0, 0, 0, 0, 0};
        for (int l = 0; l < 64; ++l)
#pragma unroll
            for (int k = 0; k < KNN; ++k)
                t5_insert(gs, gi, ls[l][k].x, __float_as_int(ls[l][k].y));
#pragma unroll
        for (int k = 0; k < KNN; ++k) sel[k] = gi[k];
    }
    __syncthreads();
    const float4* qp = (const float4*)(emb + (size_t)q * DDIM);
    float4 q0 = qp[lane * 2], q1 = qp[lane * 2 + 1];
    float ssum = 0.f;
    for (int k = 0; k < KNN; ++k) {
        const float4* mp = (const float4*)(mem + (size_t)sel[k] * DDIM);
        float4 m0 = mp[lane * 2], m1 = mp[lane * 2 + 1];
        float d0 = m0.x - q0.x, d1 = m0.y - q0.y, d2 = m0.z - q0.z, d3 = m0.w - q0.w;
        float d4 = m1.x - q1.x, d5 = m1.y - q1.y, d6 = m1.z - q1.z, d7 = m1.w - q1.w;
        float t = d0*d0 + d1*d1 + d2*d2 + d3*d3 + d4*d4 + d5*d5 + d6*d6 + d7*d7;
#pragma unroll
        for (int off = 32; off > 0; off >>= 1) t += __shfl_down(t, off);
        if (lane == 0) ssum += sqrtf(t);
    }
    if (lane == 0) qsum[q] = ssum;
}

__global__ void knn_reduce(const float* __restrict__ qsum, float* __restrict__ out, int Q) {
    const int lane = threadIdx.x;
    float v = 0.f;
    for (int i = lane; i < Q; i += 64) v += qsum[i];
#pragma unroll
    for (int off = 32; off > 0; off >>= 1) v += __shfl_down(v, off);
    if (lane == 0) out[0] = v / (float)(Q * KNN);
}

extern "C" void kernel_launch(void* const* d_in, const int* in_sizes, int n_in,
                              void* d_out, int out_size, void* d_ws, size_t ws_size,
                              hipStream_t stream) {
    (void)n_in; (void)out_size; (void)ws_size;
    const float* emb = (const float*)d_in[0];
    const float* mem = (const float*)d_in[1];
    const int Q   = in_sizes[0] / DDIM;       // 256
    const int N   = in_sizes[1] / DDIM;       // 200000
    const int NCH = (N + CROWS - 1) / CROWS;  // 1563

    float*          cand  = (float*)d_ws;                                        // Q*NCH*5*4B ~ 8 MB
    float*          qsum  = (float*)((char*)d_ws + (size_t)Q * NCH * KNN * 4);   // 1 KB
    unsigned short* qfrag = (unsigned short*)((char*)d_ws + (size_t)Q * NCH * KNN * 4 + 1024);

    conv_q<<<64, 256, 0, stream>>>(emb, qfrag);
    knn_partial<<<NCH * 2, NT, 0, stream>>>(mem, qfrag, cand, N, NCH);
    knn_merge_exact<<<Q, 64, 0, stream>>>(emb, mem, cand, qsum, Q, NCH);
    knn_reduce<<<1, 64, 0, stream>>>(qsum, (float*)d_out, Q);
}

// Round 15
// 201.079 us; speedup vs baseline: 3.1578x; 1.1793x over previous
//
#include <hip/hip_runtime.h>
#include <hip/hip_bf16.h>
#include <math.h>
#include <stdint.h>

#define DDIM 512
#define QN   256
#define MT   128            // rows per block
#define WAVES 8
#define NT   512
#define KNN  5
#define BK   32
#define NSTEP (DDIM / BK)   // 16
#define BIGF 3.0e38f

typedef __attribute__((ext_vector_type(8))) short bf16x8;
typedef __attribute__((ext_vector_type(4))) float f32x4;

#define SB0() __builtin_amdgcn_sched_barrier(0)

// async global->LDS: dest = wave-uniform base (HW adds lane*16); source is
// per-lane. qfrag is pre-permuted to lane order so each gload reads 1KB linear.
__device__ __forceinline__ void gload16(const void* g, void* l) {
    __builtin_amdgcn_global_load_lds(
        (const __attribute__((address_space(1))) void*)g,
        (__attribute__((address_space(3))) void*)l, 16, 0, 0);
}

__device__ __forceinline__ bf16x8 pack8(float4 a, float4 b) {
    union { bf16x8 v; __hip_bfloat162 h[4]; } u;
    u.h[0] = __float22bfloat162_rn(make_float2(a.x, a.y));
    u.h[1] = __float22bfloat162_rn(make_float2(a.z, a.w));
    u.h[2] = __float22bfloat162_rn(make_float2(b.x, b.y));
    u.h[3] = __float22bfloat162_rn(make_float2(b.z, b.w));
    return u.v;
}
__device__ __forceinline__ float sq8(float4 a, float4 b, float s) {
    s = fmaf(a.x,a.x,s); s = fmaf(a.y,a.y,s); s = fmaf(a.z,a.z,s); s = fmaf(a.w,a.w,s);
    s = fmaf(b.x,b.x,s); s = fmaf(b.y,b.y,s); s = fmaf(b.z,b.z,s); s = fmaf(b.w,b.w,s);
    return s;
}

// Packed top-5 insert (idx in low 7 mantissa bits). Static indices only.
__device__ __forceinline__ void t5p_insert(float (&s)[KNN], float v) {
    if (v < s[4]) {
        s[4] = v;
        if (s[4] < s[3]) { float t = s[3]; s[3] = s[4]; s[4] = t; }
        if (s[3] < s[2]) { float t = s[2]; s[2] = s[3]; s[3] = t; }
        if (s[2] < s[1]) { float t = s[1]; s[1] = s[2]; s[2] = t; }
        if (s[1] < s[0]) { float t = s[0]; s[0] = s[1]; s[1] = t; }
    }
}
__device__ __forceinline__ void t5_insert(float (&s)[KNN], int (&ix)[KNN], float v, int vi) {
    if (v < s[4]) {
        s[4] = v; ix[4] = vi;
        if (s[4] < s[3]) { float t = s[3]; s[3] = s[4]; s[4] = t; int u = ix[3]; ix[3] = ix[4]; ix[4] = u; }
        if (s[3] < s[2]) { float t = s[2]; s[2] = s[3]; s[3] = t; int u = ix[2]; ix[2] = ix[3]; ix[3] = u; }
        if (s[2] < s[1]) { float t = s[1]; s[1] = s[2]; s[2] = t; int u = ix[1]; ix[1] = ix[2]; ix[2] = u; }
        if (s[1] < s[0]) { float t = s[0]; s[0] = s[1]; s[1] = t; int u = ix[0]; ix[0] = ix[1]; ix[1] = u; }
    }
}

// Phase 0: queries f32 -> bf16 in LANE-ORDER fragment layout:
// qfrag[qb][ks][lane]*16B, lane = lq*16 + l15  <->  (q = qb*16+l15, k = ks*32+lq*8)
__global__ void conv_q(const float* __restrict__ emb, unsigned short* __restrict__ qfrag) {
    int t = blockIdx.x * 256 + threadIdx.x;     // 16384 threads: [qb][ks][lane]
    int l   = t & 63;
    int ks  = (t >> 6) & 15;
    int qb  = t >> 10;
    int q   = qb * 16 + (l & 15);
    int k   = ks * 32 + (l >> 4) * 8;
    const float* p = emb + (size_t)q * DDIM + k;
    float4 f0 = *(const float4*)(p);
    float4 f1 = *(const float4*)(p + 4);
    *(bf16x8*)(qfrag + (size_t)t * 8) = pack8(f0, f1);
}

// Phase A: 128-row chunks; 8 waves = 2 rw x 4 qw grid of 64x64 output tiles.
// A & B in lane-order LDS frags (conflict-free). B: 3-buffer ring, gloads for
// step s+2 issued at TOP of step s (flight ~2 steps); the A-pack's implicit
// vmcnt(2) at the bottom drains B(s+1) before the barrier -> race-free with
// no explicit top wait. A: reg->pack->ds_write, depth 1 (proven spill-free).
__global__ __launch_bounds__(NT, 4) void knn_partial(
        const float* __restrict__ mem, const unsigned short* __restrict__ qfrag,
        float* __restrict__ cand, int N) {
    __shared__ union {
        struct { char a[2][8192]; char b[3][16384]; } k;  // 64 KB (K-loop)
        float mbuf[2][QN][KNN];                           // 10 KB (epilogue)
    } sm;
    __shared__ float smsq[MT];

    const int tid  = threadIdx.x;
    const int lane = tid & 63;
    const int w    = tid >> 6;          // 0..7
    const int l15  = lane & 15;
    const int lq   = lane >> 4;
    const int rw   = w & 1;             // row-half (rows rw*64..+63)
    const int qw   = w >> 1;            // q-quarter (q qw*64..+63)
    const int chunk = blockIdx.x;
    const int rbase = chunk * MT;

    // stager: wave w owns rows w*16..+15 (each mem byte read once per dispatch)
    int srow = rbase + w * 16 + l15; if (srow >= N) srow = N - 1;
    const float* pA = mem + (size_t)srow * DDIM + lq * 8;
    // B staging: wave w stages frags 2w, 2w+1; source contiguous 1 KB per gload
    const char* qsB0 = (const char*)qfrag + (size_t)(2 * w)     * 16384 + lane * 16;
    const char* qsB1 = (const char*)qfrag + (size_t)(2 * w + 1) * 16384 + lane * 16;

    f32x4 acc[4][4];
    const f32x4 z4 = {0.f, 0.f, 0.f, 0.f};
#pragma unroll
    for (int rf = 0; rf < 4; ++rf)
#pragma unroll
        for (int g = 0; g < 4; ++g) acc[rf][g] = z4;
    float sq = 0.f;

    // prologue: A(0) first (so pack's auto-wait tolerates the B gloads),
    // then B(0), B(1) gloads into ring bufs 0,1.
    {
        float4 f0 = *(const float4*)(pA);
        float4 f1 = *(const float4*)(pA + 4);
        gload16(qsB0,        sm.k.b[0] + (2 * w) * 1024);
        gload16(qsB1,        sm.k.b[0] + (2 * w + 1) * 1024);
        gload16(qsB0 + 1024, sm.k.b[1] + (2 * w) * 1024);
        gload16(qsB1 + 1024, sm.k.b[1] + (2 * w + 1) * 1024);
        sq = sq8(f0, f1, sq);
        *(bf16x8*)(sm.k.a[0] + w * 1024 + lane * 16) = pack8(f0, f1); // waits A(0)
        asm volatile("s_waitcnt vmcnt(2)" ::: "memory");   // B(0) done; B(1) flying
        asm volatile("s_waitcnt lgkmcnt(0)" ::: "memory");
        __builtin_amdgcn_s_barrier();
    }

#pragma unroll
    for (int s = 0; s < NSTEP; ++s) {
        // (entered post-barrier: B(s) in b[s%3], A(s) in a[s&1], both drained)
        float4 f0, f1;
        if (s + 1 < NSTEP) {            // A(s+1) -> regs (issued at TOP)
            f0 = *(const float4*)(pA + (s + 1) * BK);
            f1 = *(const float4*)(pA + (s + 1) * BK + 4);
        }
        if (s + 2 < NSTEP) {            // B(s+2) gloads: ~2 steps of flight
            gload16(qsB0 + (s + 2) * 1024, sm.k.b[(s + 2) % 3] + (2 * w) * 1024);
            gload16(qsB1 + (s + 2) * 1024, sm.k.b[(s + 2) % 3] + (2 * w + 1) * 1024);
        }
        SB0();                          // pin the issue group at the top
        const char* ab = sm.k.a[s & 1];
        const char* bb = sm.k.b[s % 3];
        bf16x8 ar0 = *(const bf16x8*)(ab + (rw * 4 + 0) * 1024 + lane * 16);
        bf16x8 ar1 = *(const bf16x8*)(ab + (rw * 4 + 1) * 1024 + lane * 16);
        bf16x8 ar2 = *(const bf16x8*)(ab + (rw * 4 + 2) * 1024 + lane * 16);
        bf16x8 ar3 = *(const bf16x8*)(ab + (rw * 4 + 3) * 1024 + lane * 16);
#pragma unroll
        for (int g = 0; g < 4; ++g) {   // br streamed: one frag live at a time
            bf16x8 br = *(const bf16x8*)(bb + (qw * 4 + g) * 1024 + lane * 16);
            acc[0][g] = __builtin_amdgcn_mfma_f32_16x16x32_bf16(ar0, br, acc[0][g], 0, 0, 0);
            acc[1][g] = __builtin_amdgcn_mfma_f32_16x16x32_bf16(ar1, br, acc[1][g], 0, 0, 0);
            acc[2][g] = __builtin_amdgcn_mfma_f32_16x16x32_bf16(ar2, br, acc[2][g], 0, 0, 0);
            acc[3][g] = __builtin_amdgcn_mfma_f32_16x16x32_bf16(ar3, br, acc[3][g], 0, 0, 0);
        }
        if (s + 1 < NSTEP) {
            sq = sq8(f0, f1, sq);
            // pack consumes A(s+1): compiler emits vmcnt(2) here (only B(s+2)
            // is newer) -> B(s+1) is also drained before the barrier below.
            *(bf16x8*)(sm.k.a[(s + 1) & 1] + w * 1024 + lane * 16) = pack8(f0, f1);
        }
        asm volatile("s_waitcnt lgkmcnt(0)" ::: "memory");  // my ds reads+write done
        if (s + 1 < NSTEP) __builtin_amdgcn_s_barrier();
    }

    // ||m||^2 per row (stager rows w*16..+15; reduce k-slices across lq)
    sq += __shfl_xor(sq, 16);
    sq += __shfl_xor(sq, 32);
    if (lane < 16) smsq[w * 16 + lane] = sq;
    __syncthreads();
    float rsq[4][4];
#pragma unroll
    for (int rf = 0; rf < 4; ++rf)
        *(float4*)rsq[rf] = *(const float4*)&smsq[rw * 64 + rf * 16 + lq * 4];

    // epilogue: 4 q-groups per wave -> lane top5 -> shfl merge -> mbuf
#pragma unroll
    for (int g = 0; g < 4; ++g) {
        float ts[KNN] = {BIGF, BIGF, BIGF, BIGF, BIGF};
#pragma unroll
        for (int rf = 0; rf < 4; ++rf)
#pragma unroll
            for (int e = 0; e < 4; ++e) {
                int rl = rw * 64 + rf * 16 + lq * 4 + e;      // chunk-local row
                if (rbase + rl < N) {
                    float sc = fmaf(-2.f, acc[rf][g][e], rsq[rf][e]);
                    t5p_insert(ts, __int_as_float((__float_as_int(sc) & ~127) | rl));
                }
            }
#pragma unroll
        for (int x = 16; x <= 32; x <<= 1) {
            float os[KNN];
#pragma unroll
            for (int c = 0; c < KNN; ++c) os[c] = __shfl_xor(ts[c], x);
#pragma unroll
            for (int c = 0; c < KNN; ++c) t5p_insert(ts, os[c]);
        }
        if (lane < 16) {
            int q = qw * 64 + g * 16 + lane;
#pragma unroll
            for (int c = 0; c < KNN; ++c) sm.mbuf[rw][q][c] = ts[c];
        }
    }
    __syncthreads();
    if (tid < QN) {      // query tid: merge the 2 row-halves, coalesced write
        float fsv[KNN] = {BIGF, BIGF, BIGF, BIGF, BIGF};
#pragma unroll
        for (int c = 0; c < KNN; ++c) t5p_insert(fsv, sm.mbuf[0][tid][c]);
#pragma unroll
        for (int c = 0; c < KNN; ++c) t5p_insert(fsv, sm.mbuf[1][tid][c]);
        float* dst = cand + ((size_t)chunk * QN + tid) * KNN;
#pragma unroll
        for (int c = 0; c < KNN; ++c) dst[c] = fsv[c];
    }
}

// Phase B: one wave per query: global top-5 over NC*5 packed candidates,
// gather rows, exact f32 distances (immune to bf16/packing jitter), sum.
__global__ void knn_merge_exact(const float* __restrict__ emb, const float* __restrict__ mem,
                                const float* __restrict__ cand, float* __restrict__ qsum,
                                int Q, int NC) {
    const int q = blockIdx.x;
    const int lane = threadIdx.x;  // 64
    float fs[KNN] = {BIGF, BIGF, BIGF, BIGF, BIGF};
    int   fi[KNN] = {0, 0, 0, 0, 0};
    for (int c = lane; c < NC; c += 64) {
        const float* p = cand + ((size_t)c * Q + q) * KNN;
#pragma unroll
        for (int k = 0; k < KNN; ++k) {
            float pk = p[k];
            int idx = c * MT + (__float_as_int(pk) & 127);
            t5_insert(fs, fi, pk, idx);
        }
    }
    __shared__ float2 ls[64][KNN];
    __shared__ int sel[KNN];
#pragma unroll
    for (int k = 0; k < KNN; ++k) ls[lane][k] = make_float2(fs[k], __int_as_float(fi[k]));
    __syncthreads();
    if (lane == 0) {
        float gs[KNN] = {BIGF, BIGF, BIGF, BIGF, BIGF};
        int   gi[KNN] = {0, 0, 0, 0, 0};
        for (int l = 0; l < 64; ++l)
#pragma unroll
            for (int k = 0; k < KNN; ++k)
                t5_insert(gs, gi, ls[l][k].x, __float_as_int(ls[l][k].y));
#pragma unroll
        for (int k = 0; k < KNN; ++k) sel[k] = gi[k];
    }
    __syncthreads();
    const float4* qp = (const float4*)(emb + (size_t)q * DDIM);
    float4 q0 = qp[lane * 2], q1 = qp[lane * 2 + 1];
    float ssum = 0.f;
    for (int k = 0; k < KNN; ++k) {
        const float4* mp = (const float4*)(mem + (size_t)sel[k] * DDIM);
        float4 m0 = mp[lane * 2], m1 = mp[lane * 2 + 1];
        float d0 = m0.x - q0.x, d1 = m0.y - q0.y, d2 = m0.z - q0.z, d3 = m0.w - q0.w;
        float d4 = m1.x - q1.x, d5 = m1.y - q1.y, d6 = m1.z - q1.z, d7 = m1.w - q1.w;
        float t = d0*d0 + d1*d1 + d2*d2 + d3*d3 + d4*d4 + d5*d5 + d6*d6 + d7*d7;
#pragma unroll
        for (int off = 32; off > 0; off >>= 1) t += __shfl_down(t, off);
        if (lane == 0) ssum += sqrtf(t);
    }
    if (lane == 0) qsum[q] = ssum;
}

__global__ void knn_reduce(const float* __restrict__ qsum, float* __restrict__ out, int Q) {
    const int lane = threadIdx.x;
    float v = 0.f;
    for (int i = lane; i < Q; i += 64) v += qsum[i];
#pragma unroll
    for (int off = 32; off > 0; off >>= 1) v += __shfl_down(v, off);
    if (lane == 0) out[0] = v / (float)(Q * KNN);
}

extern "C" void kernel_launch(void* const* d_in, const int* in_sizes, int n_in,
                              void* d_out, int out_size, void* d_ws, size_t ws_size,
                              hipStream_t stream) {
    (void)n_in; (void)out_size; (void)ws_size;
    const float* emb = (const float*)d_in[0];
    const float* mem = (const float*)d_in[1];
    const int Q  = in_sizes[0] / DDIM;       // 256
    const int N  = in_sizes[1] / DDIM;       // 200000
    const int NC = (N + MT - 1) / MT;        // 1563

    float*          cand  = (float*)d_ws;                                        // NC*Q*5*4B ~ 8 MB
    float*          qsum  = (float*)((char*)d_ws + (size_t)NC * Q * KNN * 4);    // 1 KB
    unsigned short* qfrag = (unsigned short*)((char*)d_ws + (size_t)NC * Q * KNN * 4 + 1024);

    conv_q<<<64, 256, 0, stream>>>(emb, qfrag);
    knn_partial<<<NC, NT, 0, stream>>>(mem, qfrag, cand, N);
    knn_merge_exact<<<Q, 64, 0, stream>>>(emb, mem, cand, qsum, Q, NC);
    knn_reduce<<<1, 64, 0, stream>>>(qsum, (float*)d_out, Q);
}

// Round 16
// 185.637 us; speedup vs baseline: 3.4204x; 1.0832x over previous
//
#include <hip/hip_runtime.h>
#include <hip/hip_bf16.h>
#include <math.h>
#include <stdint.h>

#define DDIM 512
#define QN   256
#define MT   128            // rows per block
#define WAVES 8
#define NT   512
#define KNN  5
#define BK   32
#define NSTEP (DDIM / BK)   // 16
#define BIGF 3.0e38f

typedef __attribute__((ext_vector_type(4))) float f32x4;

#define SB0() __builtin_amdgcn_sched_barrier(0)

// async global->LDS: dest = wave-uniform base (HW adds lane*16); source is
// per-lane. qfrag8 is pre-permuted to lane order so each gload reads linear.
__device__ __forceinline__ void gload16(const void* g, void* l) {
    __builtin_amdgcn_global_load_lds(
        (const __attribute__((address_space(1))) void*)g,
        (__attribute__((address_space(3))) void*)l, 16, 0, 0);
}

// 8 f32 -> 8 fp8 e4m3 packed in one i64 (2 dwords via v_cvt_pk_fp8_f32)
__device__ __forceinline__ long long pack8f8(float4 a, float4 b) {
    int d0 = 0, d1 = 0;
    d0 = __builtin_amdgcn_cvt_pk_fp8_f32(a.x, a.y, d0, false);
    d0 = __builtin_amdgcn_cvt_pk_fp8_f32(a.z, a.w, d0, true);
    d1 = __builtin_amdgcn_cvt_pk_fp8_f32(b.x, b.y, d1, false);
    d1 = __builtin_amdgcn_cvt_pk_fp8_f32(b.z, b.w, d1, true);
    union { int2 i2; long long ll; } u; u.i2 = make_int2(d0, d1);
    return u.ll;
}
__device__ __forceinline__ float sq8(float4 a, float4 b, float s) {
    s = fmaf(a.x,a.x,s); s = fmaf(a.y,a.y,s); s = fmaf(a.z,a.z,s); s = fmaf(a.w,a.w,s);
    s = fmaf(b.x,b.x,s); s = fmaf(b.y,b.y,s); s = fmaf(b.z,b.z,s); s = fmaf(b.w,b.w,s);
    return s;
}

// Packed top-5 insert (idx in low 7 mantissa bits). Static indices only.
__device__ __forceinline__ void t5p_insert(float (&s)[KNN], float v) {
    if (v < s[4]) {
        s[4] = v;
        if (s[4] < s[3]) { float t = s[3]; s[3] = s[4]; s[4] = t; }
        if (s[3] < s[2]) { float t = s[2]; s[2] = s[3]; s[3] = t; }
        if (s[2] < s[1]) { float t = s[1]; s[1] = s[2]; s[2] = t; }
        if (s[1] < s[0]) { float t = s[0]; s[0] = s[1]; s[1] = t; }
    }
}
__device__ __forceinline__ void t5_insert(float (&s)[KNN], int (&ix)[KNN], float v, int vi) {
    if (v < s[4]) {
        s[4] = v; ix[4] = vi;
        if (s[4] < s[3]) { float t = s[3]; s[3] = s[4]; s[4] = t; int u = ix[3]; ix[3] = ix[4]; ix[4] = u; }
        if (s[3] < s[2]) { float t = s[2]; s[2] = s[3]; s[3] = t; int u = ix[2]; ix[2] = ix[3]; ix[3] = u; }
        if (s[2] < s[1]) { float t = s[1]; s[1] = s[2]; s[2] = t; int u = ix[1]; ix[1] = ix[2]; ix[2] = u; }
        if (s[1] < s[0]) { float t = s[0]; s[0] = s[1]; s[1] = t; int u = ix[0]; ix[0] = ix[1]; ix[1] = u; }
    }
}

// Phase 0: queries f32 -> fp8 e4m3, LANE-ORDER frag layout:
// byte = ks*8192 + qb*512 + lane*8  <->  (q = qb*16+(lane&15), k = ks*32+(lane>>4)*8)
__global__ void conv_q(const float* __restrict__ emb, char* __restrict__ qfrag8) {
    int t  = blockIdx.x * 256 + threadIdx.x;    // 16384 threads, 8 B out each
    int l  = t & 63;
    int ks = (t >> 6) & 15;
    int qb = t >> 10;
    int q  = qb * 16 + (l & 15);
    int k  = ks * 32 + (l >> 4) * 8;
    const float* p = emb + (size_t)q * DDIM + k;
    float4 f0 = *(const float4*)(p);
    float4 f1 = *(const float4*)(p + 4);
    *(long long*)(qfrag8 + (size_t)ks * 8192 + qb * 512 + l * 8) = pack8f8(f0, f1);
}

// Phase A: 128-row chunks; 8 waves = 2 rw x 4 qw grid of 64x64 output tiles.
// FP8 scoring GEMM (ranking only; phase B recomputes exact f32 distances).
// A & B in lane-order fp8 LDS frags (512 B, b64 ops, conflict-free).
// B: 3-buffer ring, gload for s+2 at TOP of step s; the A-pack's implicit
// vmcnt(1) at the bottom drains B(s+1) before the barrier. A: HBM->reg->
// cvt_fp8->ds_write, depth 1.
__global__ __launch_bounds__(NT, 4) void knn_partial(
        const float* __restrict__ mem, const char* __restrict__ qfrag8,
        float* __restrict__ cand, int N) {
    __shared__ union {
        struct { char a[2][4096]; char b[3][8192]; } k;   // 32 KB (K-loop)
        float mbuf[2][QN][KNN];                           // 10 KB (epilogue)
    } sm;
    __shared__ float smsq[MT];

    const int tid  = threadIdx.x;
    const int lane = tid & 63;
    const int w    = tid >> 6;          // 0..7
    const int l15  = lane & 15;
    const int lq   = lane >> 4;
    const int rw   = w & 1;             // row-half (rows rw*64..+63)
    const int qw   = w >> 1;            // q-quarter (q qw*64..+63)
    const int chunk = blockIdx.x;
    const int rbase = chunk * MT;

    // stager: wave w owns rows w*16..+15 (each mem byte read once per dispatch)
    int srow = rbase + w * 16 + l15; if (srow >= N) srow = N - 1;
    const float* pA = mem + (size_t)srow * DDIM + lq * 8;
    // B staging: wave w stages 1 KB (frags 2w,2w+1) per step with ONE gload16
    const char* qsB = qfrag8 + (size_t)w * 1024 + lane * 16;

    f32x4 acc[4][4];
    const f32x4 z4 = {0.f, 0.f, 0.f, 0.f};
#pragma unroll
    for (int rf = 0; rf < 4; ++rf)
#pragma unroll
        for (int g = 0; g < 4; ++g) acc[rf][g] = z4;
    float sq = 0.f;

    // prologue: A(0) loads first, then B(0), B(1) gloads into ring bufs 0,1.
    {
        float4 f0 = *(const float4*)(pA);
        float4 f1 = *(const float4*)(pA + 4);
        gload16(qsB,        sm.k.b[0] + w * 1024);
        gload16(qsB + 8192, sm.k.b[1] + w * 1024);
        sq = sq8(f0, f1, sq);
        *(long long*)(sm.k.a[0] + w * 512 + lane * 8) = pack8f8(f0, f1); // waits A(0)
        asm volatile("s_waitcnt vmcnt(1)" ::: "memory");   // B(0) done; B(1) flying
        asm volatile("s_waitcnt lgkmcnt(0)" ::: "memory");
        __builtin_amdgcn_s_barrier();
    }

#pragma unroll
    for (int s = 0; s < NSTEP; ++s) {
        // (entered post-barrier: B(s) in b[s%3], A(s) in a[s&1], both drained)
        float4 f0, f1;
        if (s + 1 < NSTEP) {            // A(s+1) -> regs (issued at TOP)
            f0 = *(const float4*)(pA + (s + 1) * BK);
            f1 = *(const float4*)(pA + (s + 1) * BK + 4);
        }
        if (s + 2 < NSTEP)              // B(s+2) gload: ~2 steps of flight
            gload16(qsB + (size_t)(s + 2) * 8192, sm.k.b[(s + 2) % 3] + w * 1024);
        SB0();                          // pin the issue group at the top
        const char* ab = sm.k.a[s & 1];
        const char* bb = sm.k.b[s % 3];
        long long ar0 = *(const long long*)(ab + (rw * 4 + 0) * 512 + lane * 8);
        long long ar1 = *(const long long*)(ab + (rw * 4 + 1) * 512 + lane * 8);
        long long ar2 = *(const long long*)(ab + (rw * 4 + 2) * 512 + lane * 8);
        long long ar3 = *(const long long*)(ab + (rw * 4 + 3) * 512 + lane * 8);
#pragma unroll
        for (int g = 0; g < 4; ++g) {   // br streamed: one frag live at a time
            long long br = *(const long long*)(bb + (qw * 4 + g) * 512 + lane * 8);
            acc[0][g] = __builtin_amdgcn_mfma_f32_16x16x32_fp8_fp8(ar0, br, acc[0][g], 0, 0, 0);
            acc[1][g] = __builtin_amdgcn_mfma_f32_16x16x32_fp8_fp8(ar1, br, acc[1][g], 0, 0, 0);
            acc[2][g] = __builtin_amdgcn_mfma_f32_16x16x32_fp8_fp8(ar2, br, acc[2][g], 0, 0, 0);
            acc[3][g] = __builtin_amdgcn_mfma_f32_16x16x32_fp8_fp8(ar3, br, acc[3][g], 0, 0, 0);
        }
        if (s + 1 < NSTEP) {
            sq = sq8(f0, f1, sq);
            // pack consumes A(s+1): compiler emits vmcnt(1) here (only B(s+2)
            // is newer) -> B(s+1) is also drained before the barrier below.
            *(long long*)(sm.k.a[(s + 1) & 1] + w * 512 + lane * 8) = pack8f8(f0, f1);
        }
        asm volatile("s_waitcnt lgkmcnt(0)" ::: "memory");  // my ds reads+write done
        if (s + 1 < NSTEP) __builtin_amdgcn_s_barrier();
    }

    // ||m||^2 per row (stager rows w*16..+15; reduce k-slices across lq)
    sq += __shfl_xor(sq, 16);
    sq += __shfl_xor(sq, 32);
    if (lane < 16) smsq[w * 16 + lane] = sq;
    __syncthreads();
    float rsq[4][4];
#pragma unroll
    for (int rf = 0; rf < 4; ++rf)
        *(float4*)rsq[rf] = *(const float4*)&smsq[rw * 64 + rf * 16 + lq * 4];

    // epilogue: 4 q-groups per wave -> lane top5 -> shfl merge -> mbuf
#pragma unroll
    for (int g = 0; g < 4; ++g) {
        float ts[KNN] = {BIGF, BIGF, BIGF, BIGF, BIGF};
#pragma unroll
        for (int rf = 0; rf < 4; ++rf)
#pragma unroll
            for (int e = 0; e < 4; ++e) {
                int rl = rw * 64 + rf * 16 + lq * 4 + e;      // chunk-local row
                if (rbase + rl < N) {
                    float sc = fmaf(-2.f, acc[rf][g][e], rsq[rf][e]);
                    t5p_insert(ts, __int_as_float((__float_as_int(sc) & ~127) | rl));
                }
            }
#pragma unroll
        for (int x = 16; x <= 32; x <<= 1) {
            float os[KNN];
#pragma unroll
            for (int c = 0; c < KNN; ++c) os[c] = __shfl_xor(ts[c], x);
#pragma unroll
            for (int c = 0; c < KNN; ++c) t5p_insert(ts, os[c]);
        }
        if (lane < 16) {
            int q = qw * 64 + g * 16 + lane;
#pragma unroll
            for (int c = 0; c < KNN; ++c) sm.mbuf[rw][q][c] = ts[c];
        }
    }
    __syncthreads();
    if (tid < QN) {      // query tid: merge the 2 row-halves, coalesced write
        float fsv[KNN] = {BIGF, BIGF, BIGF, BIGF, BIGF};
#pragma unroll
        for (int c = 0; c < KNN; ++c) t5p_insert(fsv, sm.mbuf[0][tid][c]);
#pragma unroll
        for (int c = 0; c < KNN; ++c) t5p_insert(fsv, sm.mbuf[1][tid][c]);
        float* dst = cand + ((size_t)chunk * QN + tid) * KNN;
#pragma unroll
        for (int c = 0; c < KNN; ++c) dst[c] = fsv[c];
    }
}

// Phase B: one wave per query: global top-5 over NC*5 packed candidates,
// gather rows, exact f32 distances (immune to fp8 ranking jitter), sum.
__global__ void knn_merge_exact(const float* __restrict__ emb, const float* __restrict__ mem,
                                const float* __restrict__ cand, float* __restrict__ qsum,
                                int Q, int NC) {
    const int q = blockIdx.x;
    const int lane = threadIdx.x;  // 64
    float fs[KNN] = {BIGF, BIGF, BIGF, BIGF, BIGF};
    int   fi[KNN] = {0, 0, 0, 0, 0};
    for (int c = lane; c < NC; c += 64) {
        const float* p = cand + ((size_t)c * Q + q) * KNN;
#pragma unroll
        for (int k = 0; k < KNN; ++k) {
            float pk = p[k];
            int idx = c * MT + (__float_as_int(pk) & 127);
            t5_insert(fs, fi, pk, idx);
        }
    }
    __shared__ float2 ls[64][KNN];
    __shared__ int sel[KNN];
#pragma unroll
    for (int k = 0; k < KNN; ++k) ls[lane][k] = make_float2(fs[k], __int_as_float(fi[k]));
    __syncthreads();
    if (lane == 0) {
        float gs[KNN] = {BIGF, BIGF, BIGF, BIGF, BIGF};
        int   gi[KNN] = {0, 0, 0, 0, 0};
        for (int l = 0; l < 64; ++l)
#pragma unroll
            for (int k = 0; k < KNN; ++k)
                t5_insert(gs, gi, ls[l][k].x, __float_as_int(ls[l][k].y));
#pragma unroll
        for (int k = 0; k < KNN; ++k) sel[k] = gi[k];
    }
    __syncthreads();
    const float4* qp = (const float4*)(emb + (size_t)q * DDIM);
    float4 q0 = qp[lane * 2], q1 = qp[lane * 2 + 1];
    float ssum = 0.f;
    for (int k = 0; k < KNN; ++k) {
        const float4* mp = (const float4*)(mem + (size_t)sel[k] * DDIM);
        float4 m0 = mp[lane * 2], m1 = mp[lane * 2 + 1];
        float d0 = m0.x - q0.x, d1 = m0.y - q0.y, d2 = m0.z - q0.z, d3 = m0.w - q0.w;
        float d4 = m1.x - q1.x, d5 = m1.y - q1.y, d6 = m1.z - q1.z, d7 = m1.w - q1.w;
        float t = d0*d0 + d1*d1 + d2*d2 + d3*d3 + d4*d4 + d5*d5 + d6*d6 + d7*d7;
#pragma unroll
        for (int off = 32; off > 0; off >>= 1) t += __shfl_down(t, off);
        if (lane == 0) ssum += sqrtf(t);
    }
    if (lane == 0) qsum[q] = ssum;
}

__global__ void knn_reduce(const float* __restrict__ qsum, float* __restrict__ out, int Q) {
    const int lane = threadIdx.x;
    float v = 0.f;
    for (int i = lane; i < Q; i += 64) v += qsum[i];
#pragma unroll
    for (int off = 32; off > 0; off >>= 1) v += __shfl_down(v, off);
    if (lane == 0) out[0] = v / (float)(Q * KNN);
}

extern "C" void kernel_launch(void* const* d_in, const int* in_sizes, int n_in,
                              void* d_out, int out_size, void* d_ws, size_t ws_size,
                              hipStream_t stream) {
    (void)n_in; (void)out_size; (void)ws_size;
    const float* emb = (const float*)d_in[0];
    const float* mem = (const float*)d_in[1];
    const int Q  = in_sizes[0] / DDIM;       // 256
    const int N  = in_sizes[1] / DDIM;       // 200000
    const int NC = (N + MT - 1) / MT;        // 1563

    float* cand   = (float*)d_ws;                                        // NC*Q*5*4B ~ 8 MB
    float* qsum   = (float*)((char*)d_ws + (size_t)NC * Q * KNN * 4);    // 1 KB
    char*  qfrag8 = (char*)d_ws + (size_t)NC * Q * KNN * 4 + 1024;       // 128 KB

    conv_q<<<64, 256, 0, stream>>>(emb, qfrag8);
    knn_partial<<<NC, NT, 0, stream>>>(mem, qfrag8, cand, N);
    knn_merge_exact<<<Q, 64, 0, stream>>>(emb, mem, cand, qsum, Q, NC);
    knn_reduce<<<1, 64, 0, stream>>>(qsum, (float*)d_out, Q);
}